// Round 14
// baseline (273.327 us; speedup 1.0000x reference)
//
#include <hip/hip_runtime.h>
#include <math.h>

#define F_IN 128
#define HDIM 256
#define CDIM 32
#define PSH 9
#define PSZ 512        // dsts per partition
#define CHUNK 8192     // edges per partition-pass block (196 blocks; 32-edge=128B runs)

typedef __attribute__((ext_vector_type(8))) short s16x8;
typedef __attribute__((ext_vector_type(4))) float f32x4;
typedef __attribute__((ext_vector_type(2))) float f32x2;

__device__ __forceinline__ unsigned bf16_rne(float f) {
  unsigned u = __float_as_uint(f);
  u += 0x7fffu + ((u >> 16) & 1u);
  return u >> 16;
}
__device__ __forceinline__ unsigned pack2(float lo, float hi) {
  return (bf16_rne(hi) << 16) | bf16_rne(lo);
}
__device__ __forceinline__ float bflo(unsigned u) { return __uint_as_float(u << 16); }
__device__ __forceinline__ float bfhi(unsigned u) { return __uint_as_float(u & 0xffff0000u); }

// ---------------- pass 1: partition counts (+ per-block hist for pscatter) ----------------
__global__ __launch_bounds__(256) void k_pcount(const int* __restrict__ ei,
                                                int* __restrict__ pcnt,
                                                int* __restrict__ blkhist, int E) {
  __shared__ int hist[256];
  int tid = threadIdx.x;
  hist[tid] = 0;
  __syncthreads();
  int base = blockIdx.x * CHUNK;
  int n = E - base; if (n > CHUNK) n = CHUNK;
  for (int i = tid; i < n; i += 256)
    atomicAdd(&hist[ei[(size_t)E + base + i] >> PSH], 1);
  __syncthreads();
  int h = hist[tid];
  blkhist[blockIdx.x * 256 + tid] = h;
  if (h > 0) atomicAdd(&pcnt[tid], h);
}

__global__ __launch_bounds__(256) void k_pscan(const int* __restrict__ pcnt,
                                               int* __restrict__ pbase,
                                               int* __restrict__ pcur,
                                               int* __restrict__ offs,
                                               int NP, int N, int E) {
  __shared__ int sh[256];
  int tid = threadIdx.x;
  int v = (tid < NP) ? pcnt[tid] : 0;
  sh[tid] = v;
  __syncthreads();
  for (int off = 1; off < 256; off <<= 1) {
    int t = (tid >= off) ? sh[tid - off] : 0;
    __syncthreads();
    sh[tid] += t;
    __syncthreads();
  }
  if (tid < NP) { pbase[tid] = sh[tid] - v; pcur[tid] = sh[tid] - v; }
  if (tid == 0) { pbase[NP] = E; offs[N] = E; }
}

// pass 2: LDS-staged partition scatter (hist precomputed in k_pcount)
__global__ __launch_bounds__(256) void k_pscatter(const int* __restrict__ ei,
                                                  const int* __restrict__ blkhist,
                                                  int* __restrict__ pcur,
                                                  unsigned* __restrict__ pbuf, int E) {
  __shared__ int cur[256];
  int tid = threadIdx.x;
  int h = blkhist[blockIdx.x * 256 + tid];
  if (h > 0) cur[tid] = atomicAdd(&pcur[tid], h);
  __syncthreads();
  int base = blockIdx.x * CHUNK;
  int n = E - base; if (n > CHUNK) n = CHUNK;
  for (int i = tid; i < n; i += 256) {
    int s = ei[base + i];
    int d = ei[(size_t)E + base + i];
    int p = d >> PSH;
    int pos = atomicAdd(&cur[p], 1);
    pbuf[pos] = ((unsigned)s << PSH) | (unsigned)(d & (PSZ - 1));
  }
}

// fused: per-partition histogram + LDS scan -> offs/dinv, then scatter srcs with LDS cursors
__global__ __launch_bounds__(256) void k_cnt2f(const unsigned* __restrict__ pbuf,
                                               const int* __restrict__ pbase,
                                               int* __restrict__ offs,
                                               float* __restrict__ dinv,
                                               int* __restrict__ srcs, int N) {
  __shared__ int hist[PSZ];
  __shared__ int sh[256];
  int g = blockIdx.x, tid = threadIdx.x;
  hist[tid] = 0;
  hist[tid + 256] = 0;
  __syncthreads();
  int e0 = pbase[g], e1 = pbase[g + 1];
  for (int i = e0 + tid; i < e1; i += 256)
    atomicAdd(&hist[pbuf[i] & (PSZ - 1)], 1);
  __syncthreads();
  int v0 = hist[2 * tid], v1 = hist[2 * tid + 1];
  int s = v0 + v1;
  sh[tid] = s;
  __syncthreads();
  for (int off = 1; off < 256; off <<= 1) {
    int t = (tid >= off) ? sh[tid - off] : 0;
    __syncthreads();
    sh[tid] += t;
    __syncthreads();
  }
  int run = pbase[g] + sh[tid] - s;
  int d = (g << PSH) + 2 * tid;
  if (d < N) { offs[d] = run; dinv[d] = rsqrtf((float)v0 + 1.0f); }
  if (d + 1 < N) { offs[d + 1] = run + v0; dinv[d + 1] = rsqrtf((float)v1 + 1.0f); }
  __syncthreads();
  hist[2 * tid] = run;            // reuse hist as cursors
  hist[2 * tid + 1] = run + v0;
  __syncthreads();
  for (int i = e0 + tid; i < e1; i += 256) {
    unsigned v = pbuf[i];
    int pos = atomicAdd(&hist[v & (PSZ - 1)], 1);
    srcs[pos] = (int)(v >> PSH);
  }
}

// ---------------- conversions ----------------
// xh' = x * dinv[row], bf16-packed (runs AFTER cnt2f)
__global__ void k_cvt_x(const float2* __restrict__ x, const float* __restrict__ dinv,
                        unsigned* __restrict__ xh, long long n2) {
  long long i = (long long)blockIdx.x * blockDim.x + threadIdx.x;
  if (i >= n2) return;
  float2 v = x[i];
  float sc = dinv[(int)(i >> 6)];
  xh[i] = pack2(v.x * sc, v.y * sc);
}

__global__ void k_cvt_w(const float* __restrict__ W1, const float* __restrict__ W2,
                        short* __restrict__ W1t, short* __restrict__ W2t) {
  int t = blockIdx.x * blockDim.x + threadIdx.x;
  if (t < F_IN * HDIM) {
    int c = t >> 7, k = t & 127;
    W1t[t] = (short)bf16_rne(W1[k * HDIM + c]);
  } else {
    int t2 = t - F_IN * HDIM;
    if (t2 < HDIM * CDIM) {
      int n = t2 >> 8, k = t2 & 255;
      W2t[t2] = (short)bf16_rne(W2[k * CDIM + n]);
    }
  }
}

// ---------------- fused layer-1: gather 32 rows to LDS, then GEMM1 MFMA + bias + relu ----------------
__global__ __launch_bounds__(256) void k_agg1g(const uint4* __restrict__ xh4,
                                               const int* __restrict__ srcs,
                                               const int* __restrict__ offs,
                                               const float* __restrict__ dinv,
                                               const short* __restrict__ w1t,
                                               const float* __restrict__ b1,
                                               short* __restrict__ h1, int N) {
  __shared__ short hs[32 * 128];   // 8 KB: 32 rows x 256B, XOR-swizzled (byte ^= (row&7)<<4)
  int tid = threadIdx.x;
  int wid = tid >> 6;
  int lane = tid & 63;
  int row0 = blockIdx.x * 32;
  int grp = lane >> 4;   // 4 edge streams
  int gl = lane & 15;    // 16 lanes x 16B = 256B row

  // ---- gather phase: each wave handles 8 rows ----
  for (int rr = 0; rr < 8; ++rr) {
    int rl = wid * 8 + rr;
    int row = row0 + rl;
    if (row >= N) break;
    float dd = dinv[row];
    f32x2 a0 = {0.f, 0.f}, a1 = {0.f, 0.f}, a2 = {0.f, 0.f}, a3 = {0.f, 0.f};
    if (grp == 0) {  // self loop: xh'[row]
      uint4 u = xh4[(size_t)row * 16 + gl];
      a0 = (f32x2){bflo(u.x), bfhi(u.x)};
      a1 = (f32x2){bflo(u.y), bfhi(u.y)};
      a2 = (f32x2){bflo(u.z), bfhi(u.z)};
      a3 = (f32x2){bflo(u.w), bfhi(u.w)};
    }
    int beg = offs[row], end = offs[row + 1];
    int k = beg + grp;
#define ACC1(V)                                   \
    a0 += (f32x2){bflo(V.x), bfhi(V.x)};          \
    a1 += (f32x2){bflo(V.y), bfhi(V.y)};          \
    a2 += (f32x2){bflo(V.z), bfhi(V.z)};          \
    a3 += (f32x2){bflo(V.w), bfhi(V.w)};
    while (k + 12 < end) {
      int s0 = srcs[k];
      int s1 = srcs[k + 4];
      int s2 = srcs[k + 8];
      int s3 = srcs[k + 12];
      uint4 v0 = xh4[(size_t)s0 * 16 + gl];
      uint4 v1 = xh4[(size_t)s1 * 16 + gl];
      uint4 v2 = xh4[(size_t)s2 * 16 + gl];
      uint4 v3 = xh4[(size_t)s3 * 16 + gl];
      ACC1(v0) ACC1(v1) ACC1(v2) ACC1(v3)
      k += 16;
    }
    while (k < end) {
      int s0 = srcs[k];
      uint4 v0 = xh4[(size_t)s0 * 16 + gl];
      ACC1(v0)
      k += 4;
    }
#undef ACC1
#define RED(A) \
    A.x += __shfl_xor(A.x, 16, 64); A.x += __shfl_xor(A.x, 32, 64); \
    A.y += __shfl_xor(A.y, 16, 64); A.y += __shfl_xor(A.y, 32, 64);
    RED(a0) RED(a1) RED(a2) RED(a3)
#undef RED
    if (grp == 0) {
      uint4 o;
      o.x = pack2(a0.x * dd, a0.y * dd);
      o.y = pack2(a1.x * dd, a1.y * dd);
      o.z = pack2(a2.x * dd, a2.y * dd);
      o.w = pack2(a3.x * dd, a3.y * dd);
      int byteoff = rl * 256 + ((gl * 16) ^ ((rl & 7) << 4));
      *(uint4*)((char*)hs + byteoff) = o;
    }
  }
  __syncthreads();

  // ---- MFMA phase: h-tile = relu(hs x W1t + b1) -> h1 ----
  int col0 = wid * 64;
  int r = lane & 15, g = lane >> 4;

  s16x8 bfrag[4][4];
  const short* wp = w1t + (size_t)(col0 + r) * F_IN + g * 8;
#pragma unroll
  for (int cf = 0; cf < 4; ++cf)
#pragma unroll
    for (int ks = 0; ks < 4; ++ks)
      bfrag[cf][ks] = *(const s16x8*)(wp + cf * 16 * F_IN + ks * 32);

  f32x4 acc[2][4] = {};
#pragma unroll
  for (int ks = 0; ks < 4; ++ks) {
    int cb = (g * 8 + ks * 32) * 2;  // byte col
    int bo0 = r * 256 + (cb ^ ((r & 7) << 4));
    int bo1 = (r + 16) * 256 + (cb ^ ((r & 7) << 4));
    s16x8 a0 = *(const s16x8*)((const char*)hs + bo0);
    s16x8 a1 = *(const s16x8*)((const char*)hs + bo1);
#pragma unroll
    for (int cf = 0; cf < 4; ++cf) {
      acc[0][cf] = __builtin_amdgcn_mfma_f32_16x16x32_bf16(a0, bfrag[cf][ks], acc[0][cf], 0, 0, 0);
      acc[1][cf] = __builtin_amdgcn_mfma_f32_16x16x32_bf16(a1, bfrag[cf][ks], acc[1][cf], 0, 0, 0);
    }
  }

  float bb[4];
#pragma unroll
  for (int cf = 0; cf < 4; ++cf) bb[cf] = b1[col0 + cf * 16 + r];
#pragma unroll
  for (int rf = 0; rf < 2; ++rf)
#pragma unroll
    for (int cf = 0; cf < 4; ++cf)
#pragma unroll
      for (int j = 0; j < 4; ++j) {
        int orow = row0 + rf * 16 + g * 4 + j;
        if (orow < N) {
          float v = fmaxf(acc[rf][cf][j] + bb[cf], 0.f);
          h1[(size_t)orow * HDIM + col0 + cf * 16 + r] = (short)bf16_rne(v);
        }
      }
}

// ---------------- GEMM2 MFMA: h1 -> Th' = (h1 x W2t) * dinv[row], bf16 ----------------
__global__ __launch_bounds__(256) void k_gemm2(const short* __restrict__ h1,
                                               const short* __restrict__ w2t,
                                               const float* __restrict__ dinv,
                                               short* __restrict__ Th, int M) {
  int wid = threadIdx.x >> 6;
  int lane = threadIdx.x & 63;
  int row0 = blockIdx.x * 128 + wid * 32;
  int r = lane & 15, g = lane >> 4;

  s16x8 bfrag[2][8];
  const short* wp = w2t + (size_t)r * HDIM + g * 8;
#pragma unroll
  for (int cf = 0; cf < 2; ++cf)
#pragma unroll
    for (int ks = 0; ks < 8; ++ks)
      bfrag[cf][ks] = *(const s16x8*)(wp + cf * 16 * HDIM + ks * 32);

  f32x4 acc[2][2] = {};
  const short* ap = h1 + (size_t)(row0 + r) * HDIM + g * 8;
#pragma unroll
  for (int ks = 0; ks < 8; ++ks) {
    s16x8 a0 = *(const s16x8*)(ap + ks * 32);
    s16x8 a1 = *(const s16x8*)(ap + 16 * HDIM + ks * 32);
#pragma unroll
    for (int cf = 0; cf < 2; ++cf) {
      acc[0][cf] = __builtin_amdgcn_mfma_f32_16x16x32_bf16(a0, bfrag[cf][ks], acc[0][cf], 0, 0, 0);
      acc[1][cf] = __builtin_amdgcn_mfma_f32_16x16x32_bf16(a1, bfrag[cf][ks], acc[1][cf], 0, 0, 0);
    }
  }
#pragma unroll
  for (int rf = 0; rf < 2; ++rf)
#pragma unroll
    for (int cf = 0; cf < 2; ++cf)
#pragma unroll
      for (int j = 0; j < 4; ++j) {
        int orow = row0 + rf * 16 + g * 4 + j;
        if (orow < M) {
          float sc = dinv[orow];
          Th[(size_t)orow * CDIM + cf * 16 + r] = (short)bf16_rne(acc[rf][cf][j] * sc);
        }
      }
}

// ---------------- layer-2 aggregation + bias + log_softmax: 8 streams x 8 lanes ----------------
__global__ __launch_bounds__(256) void k_agg2(const unsigned* __restrict__ Th,
                                              const int* __restrict__ srcs,
                                              const int* __restrict__ offs,
                                              const float* __restrict__ dinv,
                                              const float* __restrict__ b2,
                                              float* __restrict__ out, int N) {
  int row = (blockIdx.x * 256 + threadIdx.x) >> 6;
  int lane = threadIdx.x & 63;
  if (row >= N) return;
  int grp = lane >> 3;   // 8 edge streams
  int gl = lane & 7;     // 8 lanes x 8B (4 bf16) = 64B row
  float dd = dinv[row];
  float a0 = 0.f, a1 = 0.f, a2 = 0.f, a3 = 0.f;
  if (grp == 0) {  // self loop: Th'[row]
    uint2 u = ((const uint2*)Th)[(size_t)row * 8 + gl];
    a0 = bflo(u.x); a1 = bfhi(u.x);
    a2 = bflo(u.y); a3 = bfhi(u.y);
  }
  int beg = offs[row], end = offs[row + 1];
  int k = beg + grp;
#define ACC2(U)                                   \
  a0 += bflo(U.x); a1 += bfhi(U.x);               \
  a2 += bflo(U.y); a3 += bfhi(U.y);
  while (k + 24 < end) {
    int s0 = srcs[k];
    int s1 = srcs[k + 8];
    int s2 = srcs[k + 16];
    int s3 = srcs[k + 24];
    uint2 u0 = ((const uint2*)Th)[(size_t)s0 * 8 + gl];
    uint2 u1 = ((const uint2*)Th)[(size_t)s1 * 8 + gl];
    uint2 u2 = ((const uint2*)Th)[(size_t)s2 * 8 + gl];
    uint2 u3 = ((const uint2*)Th)[(size_t)s3 * 8 + gl];
    ACC2(u0) ACC2(u1) ACC2(u2) ACC2(u3)
    k += 32;
  }
  while (k < end) {
    int s0 = srcs[k];
    uint2 u0 = ((const uint2*)Th)[(size_t)s0 * 8 + gl];
    ACC2(u0)
    k += 8;
  }
#undef ACC2
  // cross-stream reduction (streams differ in lane bits 3..5)
  a0 += __shfl_xor(a0, 8, 64); a0 += __shfl_xor(a0, 16, 64); a0 += __shfl_xor(a0, 32, 64);
  a1 += __shfl_xor(a1, 8, 64); a1 += __shfl_xor(a1, 16, 64); a1 += __shfl_xor(a1, 32, 64);
  a2 += __shfl_xor(a2, 8, 64); a2 += __shfl_xor(a2, 16, 64); a2 += __shfl_xor(a2, 32, 64);
  a3 += __shfl_xor(a3, 8, 64); a3 += __shfl_xor(a3, 16, 64); a3 += __shfl_xor(a3, 32, 64);
  // final scale + bias
  float4 bb = ((const float4*)b2)[gl];
  a0 = a0 * dd + bb.x;
  a1 = a1 * dd + bb.y;
  a2 = a2 * dd + bb.z;
  a3 = a3 * dd + bb.w;
  // log_softmax over 32 classes: 8 lanes x 4 features each
  float m = fmaxf(fmaxf(a0, a1), fmaxf(a2, a3));
#pragma unroll
  for (int w = 4; w >= 1; w >>= 1) m = fmaxf(m, __shfl_xor(m, w, 64));
  float ssum = __expf(a0 - m) + __expf(a1 - m) + __expf(a2 - m) + __expf(a3 - m);
#pragma unroll
  for (int w = 4; w >= 1; w >>= 1) ssum += __shfl_xor(ssum, w, 64);
  float ls = m + __logf(ssum);
  if (grp == 0) {
    float4 o;
    o.x = a0 - ls;
    o.y = a1 - ls;
    o.z = a2 - ls;
    o.w = a3 - ls;
    ((float4*)out)[(size_t)row * 8 + gl] = o;
  }
}

extern "C" void kernel_launch(void* const* d_in, const int* in_sizes, int n_in,
                              void* d_out, int out_size, void* d_ws, size_t ws_size,
                              hipStream_t stream) {
  const float* x  = (const float*)d_in[0];
  const int*   ei = (const int*)d_in[1];
  const float* W1 = (const float*)d_in[2];
  const float* b1 = (const float*)d_in[3];
  const float* W2 = (const float*)d_in[4];
  const float* b2 = (const float*)d_in[5];
  float* out = (float*)d_out;
  int N = in_sizes[0] / F_IN;
  int E = in_sizes[1] / 2;

  int nc = (E + CHUNK - 1) / CHUNK;
  int NP = (N + PSZ - 1) >> PSH;

  char* base = (char*)d_ws;
  size_t o = 0;
  auto carve = [&](size_t bytes) { char* p = base + o; o += (bytes + 255) & ~(size_t)255; return p; };
  float*    dinv  = (float*)carve((size_t)N * 4);
  int*      offs  = (int*)carve((size_t)(N + 1) * 4);
  int*      srcs  = (int*)carve((size_t)E * 4);
  unsigned* xh    = (unsigned*)carve((size_t)N * 64 * 4);
  short*    h1    = (short*)carve((size_t)N * HDIM * 2);
  short*    Th    = (short*)carve((size_t)N * CDIM * 2);
  short*    W1t   = (short*)carve((size_t)HDIM * F_IN * 2);
  short*    W2t   = (short*)carve((size_t)CDIM * HDIM * 2);

  // CSR scratch lives in h1 (dead until k_agg1g writes it)
  int*      pcnt  = (int*)h1;                 // 256
  int*      pbase = pcnt + 256;               // NP+1 (+pad)
  int*      pcur  = pbase + 512;              // 256
  int*      blkhist = pcur + 256;             // nc*256
  unsigned* pbuf  = (unsigned*)(blkhist + (size_t)nc * 256);  // E

  // partition build -> dinv/offs/srcs
  hipMemsetAsync(pcnt, 0, 256 * 4, stream);
  k_pcount<<<nc, 256, 0, stream>>>(ei, pcnt, blkhist, E);
  k_pscan<<<1, 256, 0, stream>>>(pcnt, pbase, pcur, offs, NP, N, E);
  k_pscatter<<<nc, 256, 0, stream>>>(ei, blkhist, pcur, pbuf, E);
  k_cnt2f<<<NP, 256, 0, stream>>>(pbuf, pbase, offs, dinv, srcs, N);

  // conversions (xh' = x * dinv)
  long long n2 = (long long)N * 64;
  k_cvt_x<<<(int)((n2 + 255) / 256), 256, 0, stream>>>((const float2*)x, dinv, xh, n2);
  k_cvt_w<<<(F_IN * HDIM + HDIM * CDIM + 255) / 256, 256, 0, stream>>>(W1, W2, W1t, W2t);

  // layer 1 (fused gather + GEMM1)
  k_agg1g<<<(N + 31) / 32, 256, 0, stream>>>((const uint4*)xh, srcs, offs, dinv, W1t, b1, h1, N);

  // layer 2
  k_gemm2<<<(N + 127) / 128, 256, 0, stream>>>(h1, W2t, dinv, Th, N);
  k_agg2<<<(N + 3) / 4, 256, 0, stream>>>((const unsigned*)Th, srcs, offs, dinv, b2, out, N);
}

// Round 15
// 252.983 us; speedup vs baseline: 1.0804x; 1.0804x over previous
//
#include <hip/hip_runtime.h>
#include <math.h>

#define F_IN 128
#define HDIM 256
#define CDIM 32
#define PSH 9
#define PSZ 512        // dsts per partition
#define CHUNK 8192     // edges per partition-pass block (196 blocks; 32-edge=128B runs)

typedef __attribute__((ext_vector_type(8))) short s16x8;
typedef __attribute__((ext_vector_type(4))) float f32x4;
typedef __attribute__((ext_vector_type(2))) float f32x2;

__device__ __forceinline__ unsigned bf16_rne(float f) {
  unsigned u = __float_as_uint(f);
  u += 0x7fffu + ((u >> 16) & 1u);
  return u >> 16;
}
__device__ __forceinline__ unsigned pack2(float lo, float hi) {
  return (bf16_rne(hi) << 16) | bf16_rne(lo);
}
__device__ __forceinline__ float bflo(unsigned u) { return __uint_as_float(u << 16); }
__device__ __forceinline__ float bfhi(unsigned u) { return __uint_as_float(u & 0xffff0000u); }

// ---------------- pass 1: partition counts (+ per-block hist for pscatter) ----------------
__global__ __launch_bounds__(256) void k_pcount(const int* __restrict__ ei,
                                                int* __restrict__ pcnt,
                                                int* __restrict__ blkhist, int E) {
  __shared__ int hist[256];
  int tid = threadIdx.x;
  hist[tid] = 0;
  __syncthreads();
  int base = blockIdx.x * CHUNK;
  int n = E - base; if (n > CHUNK) n = CHUNK;
  for (int i = tid; i < n; i += 256)
    atomicAdd(&hist[ei[(size_t)E + base + i] >> PSH], 1);
  __syncthreads();
  int h = hist[tid];
  blkhist[blockIdx.x * 256 + tid] = h;
  if (h > 0) atomicAdd(&pcnt[tid], h);
}

__global__ __launch_bounds__(256) void k_pscan(const int* __restrict__ pcnt,
                                               int* __restrict__ pbase,
                                               int* __restrict__ pcur,
                                               int* __restrict__ offs,
                                               int NP, int N, int E) {
  __shared__ int sh[256];
  int tid = threadIdx.x;
  int v = (tid < NP) ? pcnt[tid] : 0;
  sh[tid] = v;
  __syncthreads();
  for (int off = 1; off < 256; off <<= 1) {
    int t = (tid >= off) ? sh[tid - off] : 0;
    __syncthreads();
    sh[tid] += t;
    __syncthreads();
  }
  if (tid < NP) { pbase[tid] = sh[tid] - v; pcur[tid] = sh[tid] - v; }
  if (tid == 0) { pbase[NP] = E; offs[N] = E; }
}

// pass 2: LDS-staged partition scatter (hist precomputed in k_pcount)
__global__ __launch_bounds__(256) void k_pscatter(const int* __restrict__ ei,
                                                  const int* __restrict__ blkhist,
                                                  int* __restrict__ pcur,
                                                  unsigned* __restrict__ pbuf, int E) {
  __shared__ int cur[256];
  int tid = threadIdx.x;
  int h = blkhist[blockIdx.x * 256 + tid];
  if (h > 0) cur[tid] = atomicAdd(&pcur[tid], h);
  __syncthreads();
  int base = blockIdx.x * CHUNK;
  int n = E - base; if (n > CHUNK) n = CHUNK;
  for (int i = tid; i < n; i += 256) {
    int s = ei[base + i];
    int d = ei[(size_t)E + base + i];
    int p = d >> PSH;
    int pos = atomicAdd(&cur[p], 1);
    pbuf[pos] = ((unsigned)s << PSH) | (unsigned)(d & (PSZ - 1));
  }
}

// per-partition histogram + LDS scan -> dinv + offs directly
__global__ __launch_bounds__(256) void k_cnt2(const unsigned* __restrict__ pbuf,
                                              const int* __restrict__ pbase,
                                              int* __restrict__ offs,
                                              float* __restrict__ dinv, int N) {
  __shared__ int hist[PSZ];
  __shared__ int sh[256];
  int g = blockIdx.x, tid = threadIdx.x;
  hist[tid] = 0;
  hist[tid + 256] = 0;
  __syncthreads();
  int e0 = pbase[g], e1 = pbase[g + 1];
  for (int i = e0 + tid; i < e1; i += 256)
    atomicAdd(&hist[pbuf[i] & (PSZ - 1)], 1);
  __syncthreads();
  int v0 = hist[2 * tid], v1 = hist[2 * tid + 1];
  int s = v0 + v1;
  sh[tid] = s;
  __syncthreads();
  for (int off = 1; off < 256; off <<= 1) {
    int t = (tid >= off) ? sh[tid - off] : 0;
    __syncthreads();
    sh[tid] += t;
    __syncthreads();
  }
  int run = pbase[g] + sh[tid] - s;
  int d = (g << PSH) + 2 * tid;
  if (d < N) { offs[d] = run; dinv[d] = rsqrtf((float)v0 + 1.0f); }
  if (d + 1 < N) { offs[d + 1] = run + v0; dinv[d + 1] = rsqrtf((float)v1 + 1.0f); }
}

// per-partition fine fill: emits 4B packed (src<<14 | dinv_bits14)
__global__ __launch_bounds__(256) void k_fillpart(const unsigned* __restrict__ pbuf,
                                                  const int* __restrict__ pbase,
                                                  const int* __restrict__ offs,
                                                  const float* __restrict__ dinv,
                                                  unsigned* __restrict__ srcs, int N) {
  __shared__ int cur[PSZ];
  int g = blockIdx.x, tid = threadIdx.x;
  int d0 = g << PSH;
  for (int i = tid; i < PSZ; i += 256) {
    int d = d0 + i;
    cur[i] = (d < N) ? offs[d] : 0;
  }
  __syncthreads();
  int e0 = pbase[g], e1 = pbase[g + 1];
  for (int i = e0 + tid; i < e1; i += 256) {
    unsigned v = pbuf[i];
    int dl = v & (PSZ - 1);
    unsigned src = v >> PSH;
    int pos = atomicAdd(&cur[dl], 1);
    unsigned db = (__float_as_uint(dinv[src]) + 0x8000u) >> 16;  // f32 bits[29:16], RNE
    srcs[pos] = (src << 14) | (db & 0x3FFFu);
  }
}

// ---------------- conversions ----------------
__global__ void k_cvt_x(const float2* __restrict__ x, unsigned* __restrict__ xh, long long n2) {
  long long i = (long long)blockIdx.x * blockDim.x + threadIdx.x;
  if (i >= n2) return;
  float2 v = x[i];
  xh[i] = pack2(v.x, v.y);
}

__global__ void k_cvt_w(const float* __restrict__ W1, const float* __restrict__ W2,
                        short* __restrict__ W1t, short* __restrict__ W2t) {
  int t = blockIdx.x * blockDim.x + threadIdx.x;
  if (t < F_IN * HDIM) {
    int c = t >> 7, k = t & 127;
    W1t[t] = (short)bf16_rne(W1[k * HDIM + c]);
  } else {
    int t2 = t - F_IN * HDIM;
    if (t2 < HDIM * CDIM) {
      int n = t2 >> 8, k = t2 & 255;
      W2t[t2] = (short)bf16_rne(W2[k * CDIM + n]);
    }
  }
}

// ---------------- layer-1 aggregation: quarter-wave, packed 4B records, f32x2 math ----------------
__global__ __launch_bounds__(256) void k_agg1(const uint4* __restrict__ xh4,
                                              const unsigned* __restrict__ srcs,
                                              const int* __restrict__ offs,
                                              const float* __restrict__ dinv,
                                              uint4* __restrict__ aggh4, int N) {
  int row = (blockIdx.x * 256 + threadIdx.x) >> 6;
  int lane = threadIdx.x & 63;
  if (row >= N) return;
  int grp = lane >> 4;   // 4 edge streams
  int gl = lane & 15;    // 16 lanes x 16B = 256B row
  float dd = dinv[row];
  f32x2 a0 = {0.f, 0.f}, a1 = {0.f, 0.f}, a2 = {0.f, 0.f}, a3 = {0.f, 0.f};
  if (grp == 0) {
    uint4 u = xh4[(size_t)row * 16 + gl];
    float sc = dd * dd;
    a0 = (f32x2){bflo(u.x) * sc, bfhi(u.x) * sc};
    a1 = (f32x2){bflo(u.y) * sc, bfhi(u.y) * sc};
    a2 = (f32x2){bflo(u.z) * sc, bfhi(u.z) * sc};
    a3 = (f32x2){bflo(u.w) * sc, bfhi(u.w) * sc};
  }
  int beg = offs[row], end = offs[row + 1];
  int k = beg + grp;
#define ACC1(V, NN)                                       \
  { f32x2 nn = {NN, NN};                                  \
    a0 += (f32x2){bflo(V.x), bfhi(V.x)} * nn;             \
    a1 += (f32x2){bflo(V.y), bfhi(V.y)} * nn;             \
    a2 += (f32x2){bflo(V.z), bfhi(V.z)} * nn;             \
    a3 += (f32x2){bflo(V.w), bfhi(V.w)} * nn; }
  while (k + 12 < end) {
    unsigned s0 = srcs[k];
    unsigned s1 = srcs[k + 4];
    unsigned s2 = srcs[k + 8];
    unsigned s3 = srcs[k + 12];
    uint4 v0 = xh4[(size_t)(s0 >> 14) * 16 + gl];
    uint4 v1 = xh4[(size_t)(s1 >> 14) * 16 + gl];
    uint4 v2 = xh4[(size_t)(s2 >> 14) * 16 + gl];
    uint4 v3 = xh4[(size_t)(s3 >> 14) * 16 + gl];
    float n0 = __uint_as_float((s0 & 0x3FFFu) << 16) * dd;
    float n1 = __uint_as_float((s1 & 0x3FFFu) << 16) * dd;
    float n2 = __uint_as_float((s2 & 0x3FFFu) << 16) * dd;
    float n3 = __uint_as_float((s3 & 0x3FFFu) << 16) * dd;
    ACC1(v0, n0) ACC1(v1, n1) ACC1(v2, n2) ACC1(v3, n3)
    k += 16;
  }
  while (k < end) {
    unsigned s0 = srcs[k];
    uint4 v0 = xh4[(size_t)(s0 >> 14) * 16 + gl];
    float n0 = __uint_as_float((s0 & 0x3FFFu) << 16) * dd;
    ACC1(v0, n0)
    k += 4;
  }
#undef ACC1
#define RED(A) \
  A.x += __shfl_xor(A.x, 16, 64); A.x += __shfl_xor(A.x, 32, 64); \
  A.y += __shfl_xor(A.y, 16, 64); A.y += __shfl_xor(A.y, 32, 64);
  RED(a0) RED(a1) RED(a2) RED(a3)
#undef RED
  if (grp == 0) {
    uint4 o;
    o.x = pack2(a0.x, a0.y);
    o.y = pack2(a1.x, a1.y);
    o.z = pack2(a2.x, a2.y);
    o.w = pack2(a3.x, a3.y);
    aggh4[(size_t)row * 16 + gl] = o;
  }
}

// ---------------- GEMM1 MFMA: aggh -> h1 bf16 (bias+relu) ----------------
__global__ __launch_bounds__(256) void k_gemm1(const short* __restrict__ aggh,
                                               const short* __restrict__ w1t,
                                               const float* __restrict__ b1,
                                               short* __restrict__ h1, int M) {
  int wid = threadIdx.x >> 6;
  int lane = threadIdx.x & 63;
  int row0 = blockIdx.x * 32;
  int col0 = wid * 64;
  int r = lane & 15, g = lane >> 4;

  s16x8 bfrag[4][4];
  const short* wp = w1t + (size_t)(col0 + r) * F_IN + g * 8;
#pragma unroll
  for (int cf = 0; cf < 4; ++cf)
#pragma unroll
    for (int ks = 0; ks < 4; ++ks)
      bfrag[cf][ks] = *(const s16x8*)(wp + cf * 16 * F_IN + ks * 32);

  f32x4 acc[2][4] = {};
  const short* ap = aggh + (size_t)(row0 + r) * F_IN + g * 8;
#pragma unroll
  for (int ks = 0; ks < 4; ++ks) {
    s16x8 a0 = *(const s16x8*)(ap + ks * 32);
    s16x8 a1 = *(const s16x8*)(ap + 16 * F_IN + ks * 32);
#pragma unroll
    for (int cf = 0; cf < 4; ++cf) {
      acc[0][cf] = __builtin_amdgcn_mfma_f32_16x16x32_bf16(a0, bfrag[cf][ks], acc[0][cf], 0, 0, 0);
      acc[1][cf] = __builtin_amdgcn_mfma_f32_16x16x32_bf16(a1, bfrag[cf][ks], acc[1][cf], 0, 0, 0);
    }
  }

  float bb[4];
#pragma unroll
  for (int cf = 0; cf < 4; ++cf) bb[cf] = b1[col0 + cf * 16 + r];
#pragma unroll
  for (int rf = 0; rf < 2; ++rf)
#pragma unroll
    for (int cf = 0; cf < 4; ++cf)
#pragma unroll
      for (int j = 0; j < 4; ++j) {
        int orow = row0 + rf * 16 + g * 4 + j;
        if (orow < M) {
          float v = fmaxf(acc[rf][cf][j] + bb[cf], 0.f);
          h1[(size_t)orow * HDIM + col0 + cf * 16 + r] = (short)bf16_rne(v);
        }
      }
}

// ---------------- GEMM2 MFMA: h1 -> Th bf16 ----------------
__global__ __launch_bounds__(256) void k_gemm2(const short* __restrict__ h1,
                                               const short* __restrict__ w2t,
                                               short* __restrict__ Th, int M) {
  int wid = threadIdx.x >> 6;
  int lane = threadIdx.x & 63;
  int row0 = blockIdx.x * 128 + wid * 32;
  int r = lane & 15, g = lane >> 4;

  s16x8 bfrag[2][8];
  const short* wp = w2t + (size_t)r * HDIM + g * 8;
#pragma unroll
  for (int cf = 0; cf < 2; ++cf)
#pragma unroll
    for (int ks = 0; ks < 8; ++ks)
      bfrag[cf][ks] = *(const s16x8*)(wp + cf * 16 * HDIM + ks * 32);

  f32x4 acc[2][2] = {};
  const short* ap = h1 + (size_t)(row0 + r) * HDIM + g * 8;
#pragma unroll
  for (int ks = 0; ks < 8; ++ks) {
    s16x8 a0 = *(const s16x8*)(ap + ks * 32);
    s16x8 a1 = *(const s16x8*)(ap + 16 * HDIM + ks * 32);
#pragma unroll
    for (int cf = 0; cf < 2; ++cf) {
      acc[0][cf] = __builtin_amdgcn_mfma_f32_16x16x32_bf16(a0, bfrag[cf][ks], acc[0][cf], 0, 0, 0);
      acc[1][cf] = __builtin_amdgcn_mfma_f32_16x16x32_bf16(a1, bfrag[cf][ks], acc[1][cf], 0, 0, 0);
    }
  }
#pragma unroll
  for (int rf = 0; rf < 2; ++rf)
#pragma unroll
    for (int cf = 0; cf < 2; ++cf)
#pragma unroll
      for (int j = 0; j < 4; ++j) {
        int orow = row0 + rf * 16 + g * 4 + j;
        if (orow < M) Th[(size_t)orow * CDIM + cf * 16 + r] = (short)bf16_rne(acc[rf][cf][j]);
      }
}

// ---------------- layer-2 aggregation + bias + log_softmax: 8 streams x 8 lanes ----------------
__global__ __launch_bounds__(256) void k_agg2(const unsigned* __restrict__ Th,
                                              const unsigned* __restrict__ srcs,
                                              const int* __restrict__ offs,
                                              const float* __restrict__ dinv,
                                              const float* __restrict__ b2,
                                              float* __restrict__ out, int N) {
  int row = (blockIdx.x * 256 + threadIdx.x) >> 6;
  int lane = threadIdx.x & 63;
  if (row >= N) return;
  int grp = lane >> 3;   // 8 edge streams
  int gl = lane & 7;     // 8 lanes x 8B (4 bf16) = 64B row
  float dd = dinv[row];
  float a0 = 0.f, a1 = 0.f, a2 = 0.f, a3 = 0.f;
  if (grp == 0) {
    uint2 u = ((const uint2*)Th)[(size_t)row * 8 + gl];
    float sc = dd * dd;
    float4 bb = ((const float4*)b2)[gl];
    a0 = bflo(u.x) * sc + bb.x;
    a1 = bfhi(u.x) * sc + bb.y;
    a2 = bflo(u.y) * sc + bb.z;
    a3 = bfhi(u.y) * sc + bb.w;
  }
  int beg = offs[row], end = offs[row + 1];
  int k = beg + grp;
#define ACC2(U, NN)                                   \
  a0 = fmaf(bflo(U.x), NN, a0); a1 = fmaf(bfhi(U.x), NN, a1); \
  a2 = fmaf(bflo(U.y), NN, a2); a3 = fmaf(bfhi(U.y), NN, a3);
  while (k + 24 < end) {
    unsigned s0 = srcs[k];
    unsigned s1 = srcs[k + 8];
    unsigned s2 = srcs[k + 16];
    unsigned s3 = srcs[k + 24];
    uint2 u0 = ((const uint2*)Th)[(size_t)(s0 >> 14) * 8 + gl];
    uint2 u1 = ((const uint2*)Th)[(size_t)(s1 >> 14) * 8 + gl];
    uint2 u2 = ((const uint2*)Th)[(size_t)(s2 >> 14) * 8 + gl];
    uint2 u3 = ((const uint2*)Th)[(size_t)(s3 >> 14) * 8 + gl];
    float n0 = __uint_as_float((s0 & 0x3FFFu) << 16) * dd;
    float n1 = __uint_as_float((s1 & 0x3FFFu) << 16) * dd;
    float n2 = __uint_as_float((s2 & 0x3FFFu) << 16) * dd;
    float n3 = __uint_as_float((s3 & 0x3FFFu) << 16) * dd;
    ACC2(u0, n0) ACC2(u1, n1) ACC2(u2, n2) ACC2(u3, n3)
    k += 32;
  }
  while (k < end) {
    unsigned s0 = srcs[k];
    uint2 u0 = ((const uint2*)Th)[(size_t)(s0 >> 14) * 8 + gl];
    float n0 = __uint_as_float((s0 & 0x3FFFu) << 16) * dd;
    ACC2(u0, n0)
    k += 8;
  }
#undef ACC2
  // cross-stream reduction (streams differ in lane bits 3..5)
  a0 += __shfl_xor(a0, 8, 64); a0 += __shfl_xor(a0, 16, 64); a0 += __shfl_xor(a0, 32, 64);
  a1 += __shfl_xor(a1, 8, 64); a1 += __shfl_xor(a1, 16, 64); a1 += __shfl_xor(a1, 32, 64);
  a2 += __shfl_xor(a2, 8, 64); a2 += __shfl_xor(a2, 16, 64); a2 += __shfl_xor(a2, 32, 64);
  a3 += __shfl_xor(a3, 8, 64); a3 += __shfl_xor(a3, 16, 64); a3 += __shfl_xor(a3, 32, 64);
  // log_softmax over 32 classes: 8 lanes x 4 features each
  float m = fmaxf(fmaxf(a0, a1), fmaxf(a2, a3));
#pragma unroll
  for (int w = 4; w >= 1; w >>= 1) m = fmaxf(m, __shfl_xor(m, w, 64));
  float ssum = __expf(a0 - m) + __expf(a1 - m) + __expf(a2 - m) + __expf(a3 - m);
#pragma unroll
  for (int w = 4; w >= 1; w >>= 1) ssum += __shfl_xor(ssum, w, 64);
  float ls = m + __logf(ssum);
  if (grp == 0) {
    float4 o;
    o.x = a0 - ls;
    o.y = a1 - ls;
    o.z = a2 - ls;
    o.w = a3 - ls;
    ((float4*)out)[(size_t)row * 8 + gl] = o;
  }
}

extern "C" void kernel_launch(void* const* d_in, const int* in_sizes, int n_in,
                              void* d_out, int out_size, void* d_ws, size_t ws_size,
                              hipStream_t stream) {
  const float* x  = (const float*)d_in[0];
  const int*   ei = (const int*)d_in[1];
  const float* W1 = (const float*)d_in[2];
  const float* b1 = (const float*)d_in[3];
  const float* W2 = (const float*)d_in[4];
  const float* b2 = (const float*)d_in[5];
  float* out = (float*)d_out;
  int N = in_sizes[0] / F_IN;
  int E = in_sizes[1] / 2;

  int nc = (E + CHUNK - 1) / CHUNK;
  int NP = (N + PSZ - 1) >> PSH;

  char* base = (char*)d_ws;
  size_t o = 0;
  auto carve = [&](size_t bytes) { char* p = base + o; o += (bytes + 255) & ~(size_t)255; return p; };
  float*    dinv  = (float*)carve((size_t)N * 4);
  int*      offs  = (int*)carve((size_t)(N + 1) * 4);
  unsigned* srcs  = (unsigned*)carve((size_t)E * 4);
  unsigned* xh    = (unsigned*)carve((size_t)N * 64 * 4);
  unsigned* aggh  = (unsigned*)carve((size_t)N * 64 * 4);
  short*    h1    = (short*)carve((size_t)N * HDIM * 2);
  short*    Th    = (short*)carve((size_t)N * CDIM * 2);
  short*    W1t   = (short*)carve((size_t)HDIM * F_IN * 2);
  short*    W2t   = (short*)carve((size_t)CDIM * HDIM * 2);

  // CSR scratch lives in h1 (dead until GEMM1 writes it)
  int*      pcnt  = (int*)h1;                 // 256
  int*      pbase = pcnt + 256;               // NP+1 (+pad)
  int*      pcur  = pbase + 512;              // 256
  int*      blkhist = pcur + 256;             // nc*256
  unsigned* pbuf  = (unsigned*)(blkhist + (size_t)nc * 256);  // E

  long long n2 = (long long)N * 64;
  k_cvt_x<<<(int)((n2 + 255) / 256), 256, 0, stream>>>((const float2*)x, xh, n2);
  k_cvt_w<<<(F_IN * HDIM + HDIM * CDIM + 255) / 256, 256, 0, stream>>>(W1, W2, W1t, W2t);

  // partition build
  hipMemsetAsync(pcnt, 0, 256 * 4, stream);
  k_pcount<<<nc, 256, 0, stream>>>(ei, pcnt, blkhist, E);
  k_pscan<<<1, 256, 0, stream>>>(pcnt, pbase, pcur, offs, NP, N, E);
  k_pscatter<<<nc, 256, 0, stream>>>(ei, blkhist, pcur, pbuf, E);
  k_cnt2<<<NP, 256, 0, stream>>>(pbuf, pbase, offs, dinv, N);
  k_fillpart<<<NP, 256, 0, stream>>>(pbuf, pbase, offs, dinv, srcs, N);

  // layer 1
  k_agg1<<<(N + 3) / 4, 256, 0, stream>>>((const uint4*)xh, srcs, offs, dinv, (uint4*)aggh, N);
  k_gemm1<<<(N + 31) / 32, 256, 0, stream>>>((const short*)aggh, W1t, b1, h1, N);

  // layer 2
  k_gemm2<<<(N + 127) / 128, 256, 0, stream>>>(h1, W2t, Th, N);
  k_agg2<<<(N + 3) / 4, 256, 0, stream>>>((const unsigned*)Th, srcs, offs, dinv, b2, out, N);
}